// Round 1
// baseline (35.388 us; speedup 1.0000x reference)
//
#include <hip/hip_runtime.h>

#define IMG_H 1024
#define IMG_W 1024

__global__ __launch_bounds__(256) void EdgePreserve_kernel(const float* __restrict__ x,
                                                           float* __restrict__ out) {
    const int t   = threadIdx.x;
    const int bid = blockIdx.x;        // b*64 + pool_row
    const int b   = bid >> 6;
    const int pr  = bid & 63;
    const int r0  = pr << 4;           // first image row of this strip
    const int c0  = t << 2;            // 4 consecutive cols per thread

    // w = exp(-(nb-x0)^2 / 8) * exp(-dist2/5000)
    //   = exp2( d*d * Cc + Ws[dist2] )
    const float Cc  = -0.1803368801111244f;   // -(1/8)*log2(e)
    const float Ws1 = -2.8853900817779270e-4f; // log2(exp(-1/5000))
    const float Ws2 = -5.7707801635558540e-4f; // log2(exp(-2/5000))

    const float* base = x + (size_t)b * (IMG_H * IMG_W);

    // halo columns with reflect (only threads 0 and 255 actually reflect)
    int cl = c0 - 1;       if (cl < 0)        cl = 1;
    int cr = c0 + 4;       if (cr > IMG_W-1)  cr = IMG_W - 2;

    float win[3][6];

    auto loadrow = [&](int r, float* dst) {
        int rr = (r < 0) ? -r : ((r >= IMG_H) ? (2*IMG_H - 2 - r) : r);
        const float* row = base + rr * IMG_W;
        float4 v = *reinterpret_cast<const float4*>(row + c0);
        dst[0] = row[cl];
        dst[1] = v.x; dst[2] = v.y; dst[3] = v.z; dst[4] = v.w;
        dst[5] = row[cr];
    };

    loadrow(r0 - 1, win[0]);
    loadrow(r0,     win[1]);

    float psum = 0.0f;

    #pragma unroll
    for (int r = 0; r < 16; ++r) {
        loadrow(r0 + r + 1, win[(r + 2) % 3]);
        const float* A  = win[r % 3];        // row above
        const float* Bw = win[(r + 1) % 3];  // center row
        const float* Cw = win[(r + 2) % 3];  // row below

        #pragma unroll
        for (int i = 0; i < 4; ++i) {
            const float x0 = Bw[i + 1];
            float num = x0;      // center: w = exp(0)*exp(0) = 1
            float den = 1.0f;

            auto acc = [&](float nb, float ws) {
                float d = nb - x0;
                float w = __builtin_amdgcn_exp2f(fmaf(d * d, Cc, ws));
                num = fmaf(w, nb, num);
                den += w;
            };

            acc(A[i],     Ws2); acc(A[i + 1], Ws1); acc(A[i + 2], Ws2);
            acc(Bw[i],    Ws1);                     acc(Bw[i + 2], Ws1);
            acc(Cw[i],    Ws2); acc(Cw[i + 1], Ws1); acc(Cw[i + 2], Ws2);

            psum += num * __builtin_amdgcn_rcpf(den);
        }
    }

    // reduce the 4 lanes that share one pool block (cols 4t..4t+3 all in block t/4)
    psum += __shfl_xor(psum, 1);
    psum += __shfl_xor(psum, 2);

    if ((t & 3) == 0) {
        out[(size_t)bid * 64 + (t >> 2)] = psum * (1.0f / 256.0f);
    }
}

extern "C" void kernel_launch(void* const* d_in, const int* in_sizes, int n_in,
                              void* d_out, int out_size, void* d_ws, size_t ws_size,
                              hipStream_t stream) {
    const float* x = (const float*)d_in[0];
    float* out     = (float*)d_out;
    // grid: 16 batches * 64 pool rows; block: 256 threads (4 cols each, 16 rows)
    EdgePreserve_kernel<<<dim3(16 * 64), dim3(256), 0, stream>>>(x, out);
}